// Round 1
// baseline (1449.332 us; speedup 1.0000x reference)
//
#include <hip/hip_runtime.h>
#include <hip/hip_bf16.h>
#include <hip/hip_fp16.h>

// LSTM: S=2048, B=128, I=128, H=128, 4H=512
// out = [h_seq (S*B*H) | h_T (B*H) | c_T (B*H)], fp32
// ws  = xg (S*B*512) fp16 = 268 MB

#define S_LEN 2048
#define BATCH 128
#define HID   128
#define G4    512

typedef _Float16 h2_t __attribute__((ext_vector_type(2)));
typedef _Float16 h8_t __attribute__((ext_vector_type(8)));
typedef float    f4_t __attribute__((ext_vector_type(4)));

// ---------------------------------------------------------------------------
// Phase 1: xg[m][n] = sum_k x[m][k]*V[n][k] + b[n] + b2[n], fp16 out, f16 MFMA
// (unchanged: ~250 us)
// ---------------------------------------------------------------------------
__global__ __launch_bounds__(256, 2)
void xg_gemm(const float* __restrict__ x, const float* __restrict__ V,
             const float* __restrict__ b, const float* __restrict__ b2,
             __half* __restrict__ xg)
{
    __shared__ h8_t As[128 * 16];   // 32 KB
    __shared__ h8_t Bs[128 * 16];   // 32 KB

    const int t  = threadIdx.x;
    const int m0 = blockIdx.y * 128;
    const int n0 = blockIdx.x * 128;

#pragma unroll
    for (int r = 0; r < 8; ++r) {
        int id  = t + 256 * r;
        int row = id >> 4;
        int j   = id & 15;
        const float4* gx = (const float4*)(x + (long)(m0 + row) * 128 + j * 8);
        float4 a0 = gx[0], a1 = gx[1];
        h8_t ha = { (_Float16)a0.x, (_Float16)a0.y, (_Float16)a0.z, (_Float16)a0.w,
                    (_Float16)a1.x, (_Float16)a1.y, (_Float16)a1.z, (_Float16)a1.w };
        As[row * 16 + (j ^ (row & 15))] = ha;
        const float4* gv = (const float4*)(V + (long)(n0 + row) * 128 + j * 8);
        float4 b0 = gv[0], b1 = gv[1];
        h8_t hb = { (_Float16)b0.x, (_Float16)b0.y, (_Float16)b0.z, (_Float16)b0.w,
                    (_Float16)b1.x, (_Float16)b1.y, (_Float16)b1.z, (_Float16)b1.w };
        Bs[row * 16 + (j ^ (row & 15))] = hb;
    }
    __syncthreads();

    const int w    = t >> 6;
    const int lane = t & 63;
    const int m    = lane & 15;
    const int quad = lane >> 4;

    f4_t acc[2][8];
#pragma unroll
    for (int i = 0; i < 2; ++i)
#pragma unroll
        for (int j = 0; j < 8; ++j) acc[i][j] = (f4_t)0.f;

#pragma unroll
    for (int ks = 0; ks < 4; ++ks) {
        int ch = ks * 4 + quad;
        h8_t a0 = As[(w * 32      + m) * 16 + (ch ^ m)];
        h8_t a1 = As[(w * 32 + 16 + m) * 16 + (ch ^ m)];
#pragma unroll
        for (int nt = 0; nt < 8; ++nt) {
            h8_t bf = Bs[(nt * 16 + m) * 16 + (ch ^ m)];
            acc[0][nt] = __builtin_amdgcn_mfma_f32_16x16x32_f16(a0, bf, acc[0][nt], 0, 0, 0);
            acc[1][nt] = __builtin_amdgcn_mfma_f32_16x16x32_f16(a1, bf, acc[1][nt], 0, 0, 0);
        }
    }

#pragma unroll
    for (int nt = 0; nt < 8; ++nt) {
        int col = n0 + nt * 16 + m;
        float bias = b[col] + b2[col];
#pragma unroll
        for (int mi = 0; mi < 2; ++mi) {
#pragma unroll
            for (int rg = 0; rg < 4; ++rg) {
                long mrow = (long)(m0 + w * 32 + mi * 16 + quad * 4 + rg);
                xg[mrow * G4 + col] = __float2half(acc[mi][nt][rg] + bias);
            }
        }
    }
}

// ---------------------------------------------------------------------------
// Phase 2: scan, MFMA edition. 128 WGs x 512 threads (8 waves).
// Wave w owns hids [16w, 16w+16). Its 4 m-tiles are W rows
// {g*128 + 16w .. +16} for g = 0..3 (gates i,f,g,o), so after
// 4 gates x 4 K-chunks of mfma_16x16x32_f16 with B = h broadcast across
// all 16 columns, EVERY lane holds all 4 gate pre-activations for hids
// 16w + quad*4 + {0..3}. Lane activates only rg = col&3 (4x redundancy,
// zero cross-lane traffic); lanes col<4 write h to LDS + global.
// Critical path/step: bar -> ds_read h frags -> 4x4 mfma -> act -> ds_write.
// ---------------------------------------------------------------------------
__device__ __forceinline__ float fsig(float x) {
    return __builtin_amdgcn_rcpf(1.f + __expf(-x));
}
__device__ __forceinline__ float ftanh(float x) {
    return 1.f - 2.f * __builtin_amdgcn_rcpf(1.f + __expf(2.f * x));
}
__device__ __forceinline__ void bar() {
    asm volatile("s_waitcnt lgkmcnt(0)" ::: "memory");
    __builtin_amdgcn_s_barrier();
    asm volatile("" ::: "memory");
}

__global__ __launch_bounds__(512, 2)
void lstm_scan(const __half* __restrict__ xg, const float* __restrict__ W,
               float* __restrict__ out)
{
    const int bidx = blockIdx.x;
    const int t    = threadIdx.x;
    const int w    = t >> 6;      // wave 0..7 -> hids [16w, 16w+16)
    const int lane = t & 63;
    const int col  = lane & 15;   // MFMA A-row / C-col index
    const int quad = lane >> 4;   // k-slice index; C rows quad*4+{0..3}
    const int rg   = col & 3;     // the C-row this lane activates
    const int hid  = 16 * w + quad * 4 + rg;

    __shared__ __align__(16) __half h_buf[2][HID];   // 512 B

    // A-frags (held in regs for the whole scan):
    // a[g][kc][j] = (f16) W[g*128 + 16w + col][kc*32 + quad*8 + j]
    h8_t a[4][4];
#pragma unroll
    for (int g = 0; g < 4; ++g) {
        const float* Wr = W + (long)(g * 128 + 16 * w + col) * 128 + quad * 8;
#pragma unroll
        for (int kc = 0; kc < 4; ++kc) {
            const float4* wp = (const float4*)(Wr + kc * 32);
            float4 v0 = wp[0], v1 = wp[1];
            a[g][kc] = h8_t{ (_Float16)v0.x, (_Float16)v0.y, (_Float16)v0.z, (_Float16)v0.w,
                             (_Float16)v1.x, (_Float16)v1.y, (_Float16)v1.z, (_Float16)v1.w };
        }
    }

    if (t < HID) h_buf[0][t] = __float2half(0.f);
    __syncthreads();

    // xg columns this lane needs: g*128 + hid, g = 0..3
    const __half* xp = xg + (long)bidx * G4 + hid;
    const long step_stride = (long)BATCH * G4;   // 65536

    __half p0[4], p1[4];
#pragma unroll
    for (int g = 0; g < 4; ++g) {
        p0[g] = xp[g * 128];
        p1[g] = xp[step_stride + g * 128];
    }

    float c = 0.f, hlast = 0.f;
    float* out_h = out + (long)bidx * HID;
    const long SBH = (long)S_LEN * BATCH * HID;

    const bool sel1 = (col & 1) != 0;
    const bool sel2 = (col & 2) != 0;

    for (int s = 0; s < S_LEN; ++s) {
        // prefetch xg for step s+2 (stays in flight across this step)
        long soff = (long)((s + 2 < S_LEN) ? s + 2 : S_LEN - 1) * step_stride;
        __half nx[4];
#pragma unroll
        for (int g = 0; g < 4; ++g) nx[g] = xp[soff + g * 128];

        // B-frags: h[kc*32 + quad*8 .. +8), quad-broadcast, conflict-free
        const h8_t* hb = (const h8_t*)(&h_buf[s & 1][0]);

        f4_t acc0 = (f4_t)0.f, acc1 = (f4_t)0.f, acc2 = (f4_t)0.f, acc3 = (f4_t)0.f;
#pragma unroll
        for (int kc = 0; kc < 4; ++kc) {
            h8_t bf = hb[kc * 4 + quad];
            acc0 = __builtin_amdgcn_mfma_f32_16x16x32_f16(a[0][kc], bf, acc0, 0, 0, 0);
            acc1 = __builtin_amdgcn_mfma_f32_16x16x32_f16(a[1][kc], bf, acc1, 0, 0, 0);
            acc2 = __builtin_amdgcn_mfma_f32_16x16x32_f16(a[2][kc], bf, acc2, 0, 0, 0);
            acc3 = __builtin_amdgcn_mfma_f32_16x16x32_f16(a[3][kc], bf, acc3, 0, 0, 0);
        }

        // static-index select of own C row (rg = col&3) + xg add
        float v01, v23;
        v01 = sel1 ? acc0[1] : acc0[0];  v23 = sel1 ? acc0[3] : acc0[2];
        float pi = (sel2 ? v23 : v01) + __half2float(p0[0]);
        v01 = sel1 ? acc1[1] : acc1[0];  v23 = sel1 ? acc1[3] : acc1[2];
        float pf = (sel2 ? v23 : v01) + __half2float(p0[1]);
        v01 = sel1 ? acc2[1] : acc2[0];  v23 = sel1 ? acc2[3] : acc2[2];
        float pg = (sel2 ? v23 : v01) + __half2float(p0[2]);
        v01 = sel1 ? acc3[1] : acc3[0];  v23 = sel1 ? acc3[3] : acc3[2];
        float po = (sel2 ? v23 : v01) + __half2float(p0[3]);

        float ia = fsig(pi);
        float fa = fsig(pf);
        float ga = ftanh(pg);
        float oa = fsig(po);
        c = fa * c + ia * ga;                 // redundant x4 across col groups
        float hv = oa * ftanh(c);
        hlast = hv;

        if (col < 4) {                        // unique writer per hid (col == rg)
            h_buf[(s + 1) & 1][hid] = __float2half(hv);
            out_h[(long)s * (BATCH * HID) + hid] = hv;   // stays in flight
        }
        bar();   // lgkmcnt-only: h visible, globals keep flowing

#pragma unroll
        for (int g = 0; g < 4; ++g) { p0[g] = p1[g]; p1[g] = nx[g]; }
    }

    if (col < 4) {
        out[SBH + (long)bidx * HID + hid]                     = hlast;  // h_T
        out[SBH + (long)BATCH * HID + (long)bidx * HID + hid] = c;      // c_T
    }
}

// ---------------------------------------------------------------------------
extern "C" void kernel_launch(void* const* d_in, const int* in_sizes, int n_in,
                              void* d_out, int out_size, void* d_ws, size_t ws_size,
                              hipStream_t stream) {
    const float* x  = (const float*)d_in[0];
    const float* V  = (const float*)d_in[1];
    const float* W  = (const float*)d_in[2];
    const float* b  = (const float*)d_in[3];
    const float* b2 = (const float*)d_in[4];
    float* out = (float*)d_out;
    __half* xg = (__half*)d_ws;   // 2048*128*512*2 = 268435456 B

    dim3 g1(G4 / 128, (S_LEN * BATCH) / 128);   // (4, 2048)
    xg_gemm<<<g1, dim3(256), 0, stream>>>(x, V, b, b2, xg);
    lstm_scan<<<dim3(BATCH), dim3(512), 0, stream>>>(xg, W, out);
}

// Round 2
// 1378.534 us; speedup vs baseline: 1.0514x; 1.0514x over previous
//
#include <hip/hip_runtime.h>
#include <hip/hip_bf16.h>
#include <hip/hip_fp16.h>

// LSTM: S=2048, B=128, I=128, H=128, 4H=512
// out = [h_seq (S*B*H) | h_T (B*H) | c_T (B*H)], fp32
// ws  = xg (S*B*512) fp16 = 268 MB

#define S_LEN 2048
#define BATCH 128
#define HID   128
#define G4    512

typedef _Float16 h2_t __attribute__((ext_vector_type(2)));
typedef _Float16 h8_t __attribute__((ext_vector_type(8)));
typedef float    f4_t __attribute__((ext_vector_type(4)));

// ---------------------------------------------------------------------------
// Phase 1: xg[m][n] = sum_k x[m][k]*V[n][k] + b[n] + b2[n], fp16 out, f16 MFMA
// (unchanged: ~250 us)
// ---------------------------------------------------------------------------
__global__ __launch_bounds__(256, 2)
void xg_gemm(const float* __restrict__ x, const float* __restrict__ V,
             const float* __restrict__ b, const float* __restrict__ b2,
             __half* __restrict__ xg)
{
    __shared__ h8_t As[128 * 16];   // 32 KB
    __shared__ h8_t Bs[128 * 16];   // 32 KB

    const int t  = threadIdx.x;
    const int m0 = blockIdx.y * 128;
    const int n0 = blockIdx.x * 128;

#pragma unroll
    for (int r = 0; r < 8; ++r) {
        int id  = t + 256 * r;
        int row = id >> 4;
        int j   = id & 15;
        const float4* gx = (const float4*)(x + (long)(m0 + row) * 128 + j * 8);
        float4 a0 = gx[0], a1 = gx[1];
        h8_t ha = { (_Float16)a0.x, (_Float16)a0.y, (_Float16)a0.z, (_Float16)a0.w,
                    (_Float16)a1.x, (_Float16)a1.y, (_Float16)a1.z, (_Float16)a1.w };
        As[row * 16 + (j ^ (row & 15))] = ha;
        const float4* gv = (const float4*)(V + (long)(n0 + row) * 128 + j * 8);
        float4 b0 = gv[0], b1 = gv[1];
        h8_t hb = { (_Float16)b0.x, (_Float16)b0.y, (_Float16)b0.z, (_Float16)b0.w,
                    (_Float16)b1.x, (_Float16)b1.y, (_Float16)b1.z, (_Float16)b1.w };
        Bs[row * 16 + (j ^ (row & 15))] = hb;
    }
    __syncthreads();

    const int w    = t >> 6;
    const int lane = t & 63;
    const int m    = lane & 15;
    const int quad = lane >> 4;

    f4_t acc[2][8];
#pragma unroll
    for (int i = 0; i < 2; ++i)
#pragma unroll
        for (int j = 0; j < 8; ++j) acc[i][j] = (f4_t)0.f;

#pragma unroll
    for (int ks = 0; ks < 4; ++ks) {
        int ch = ks * 4 + quad;
        h8_t a0 = As[(w * 32      + m) * 16 + (ch ^ m)];
        h8_t a1 = As[(w * 32 + 16 + m) * 16 + (ch ^ m)];
#pragma unroll
        for (int nt = 0; nt < 8; ++nt) {
            h8_t bf = Bs[(nt * 16 + m) * 16 + (ch ^ m)];
            acc[0][nt] = __builtin_amdgcn_mfma_f32_16x16x32_f16(a0, bf, acc[0][nt], 0, 0, 0);
            acc[1][nt] = __builtin_amdgcn_mfma_f32_16x16x32_f16(a1, bf, acc[1][nt], 0, 0, 0);
        }
    }

#pragma unroll
    for (int nt = 0; nt < 8; ++nt) {
        int col = n0 + nt * 16 + m;
        float bias = b[col] + b2[col];
#pragma unroll
        for (int mi = 0; mi < 2; ++mi) {
#pragma unroll
            for (int rg = 0; rg < 4; ++rg) {
                long mrow = (long)(m0 + w * 32 + mi * 16 + quad * 4 + rg);
                xg[mrow * G4 + col] = __float2half(acc[mi][nt][rg] + bias);
            }
        }
    }
}

// ---------------------------------------------------------------------------
// Phase 2: scan, MFMA + deep-prefetch edition. 128 WGs x 512 threads.
// Key fix this round: 4-deep xg register ring with the step loop unrolled
// x4 (all ring indices compile-time). Slot u is CONSUMED at the top of its
// iteration and immediately REFILLED for step s+4 -> the vmcnt wait lands
// on loads issued ~4 step-times earlier (>2000 cy slack vs ~900 cy HBM
// latency). The previous p0/p1 rotation in a rolled loop forced the wait
// at the end of the SAME step (register-rotation movs), pinning step time
// at HBM latency (~1360 cy) -- which is why fdot2 and MFMA variants timed
// identically.
// ---------------------------------------------------------------------------
__device__ __forceinline__ float fsig(float x) {
    return __builtin_amdgcn_rcpf(1.f + __expf(-x));
}
__device__ __forceinline__ float ftanh(float x) {
    return 1.f - 2.f * __builtin_amdgcn_rcpf(1.f + __expf(2.f * x));
}
__device__ __forceinline__ void bar() {
    asm volatile("s_waitcnt lgkmcnt(0)" ::: "memory");
    __builtin_amdgcn_s_barrier();
    asm volatile("" ::: "memory");
}

__global__ __launch_bounds__(512, 2)
void lstm_scan(const __half* __restrict__ xg, const float* __restrict__ W,
               float* __restrict__ out)
{
    const int bidx = blockIdx.x;
    const int t    = threadIdx.x;
    const int w    = t >> 6;      // wave 0..7 -> hids [16w, 16w+16)
    const int lane = t & 63;
    const int col  = lane & 15;   // MFMA A-row / C-col index
    const int quad = lane >> 4;   // k-slice index; C rows quad*4+{0..3}
    const int rg   = col & 3;     // the C-row this lane activates
    const int hid  = 16 * w + quad * 4 + rg;

    __shared__ __align__(16) __half h_buf[2][HID];   // 512 B

    // A-frags (held in regs for the whole scan):
    // a[g][kc][j] = (f16) W[g*128 + 16w + col][kc*32 + quad*8 + j]
    h8_t a[4][4];
#pragma unroll
    for (int g = 0; g < 4; ++g) {
        const float* Wr = W + (long)(g * 128 + 16 * w + col) * 128 + quad * 8;
#pragma unroll
        for (int kc = 0; kc < 4; ++kc) {
            const float4* wp = (const float4*)(Wr + kc * 32);
            float4 v0 = wp[0], v1 = wp[1];
            a[g][kc] = h8_t{ (_Float16)v0.x, (_Float16)v0.y, (_Float16)v0.z, (_Float16)v0.w,
                             (_Float16)v1.x, (_Float16)v1.y, (_Float16)v1.z, (_Float16)v1.w };
        }
    }

    if (t < HID) h_buf[0][t] = __float2half(0.f);
    __syncthreads();

    // xg columns this lane needs: g*128 + hid, g = 0..3
    const __half* xp = xg + (long)bidx * G4 + hid;
    const long step_stride = (long)BATCH * G4;   // 65536

    // 4-deep prefetch ring, all indices compile-time after unroll
    __half p[4][4];
#pragma unroll
    for (int j = 0; j < 4; ++j) {
        const __half* q = xp + (long)j * step_stride;
#pragma unroll
        for (int g = 0; g < 4; ++g) p[j][g] = q[g * 128];
    }

    float c = 0.f, hlast = 0.f;
    float* outp = out + (long)bidx * HID + hid;   // col<4 lanes write *outp
    const long SBH = (long)S_LEN * BATCH * HID;

    const bool sel1 = (col & 1) != 0;
    const bool sel2 = (col & 2) != 0;

    for (int s0 = 0; s0 < S_LEN; s0 += 4) {
#pragma unroll
        for (int u = 0; u < 4; ++u) {
            const int s = s0 + u;

            // consume slot u FIRST (vmcnt wait lands here, 4-step slack)
            float xv0 = __half2float(p[u][0]);
            float xv1 = __half2float(p[u][1]);
            float xv2 = __half2float(p[u][2]);
            float xv3 = __half2float(p[u][3]);

            // refill slot u for step s+4 (clamped; tail extras never consumed)
            {
                int sn = s + 4; sn = (sn < S_LEN) ? sn : (S_LEN - 1);
                const __half* q = xp + (long)sn * step_stride;
                p[u][0] = q[0];
                p[u][1] = q[128];
                p[u][2] = q[256];
                p[u][3] = q[384];
            }

            // B-frags: h[kc*32 + quad*8 .. +8), quad-broadcast, conflict-free
            const h8_t* hb = (const h8_t*)(&h_buf[s & 1][0]);

            f4_t acc0 = (f4_t)0.f, acc1 = (f4_t)0.f, acc2 = (f4_t)0.f, acc3 = (f4_t)0.f;
#pragma unroll
            for (int kc = 0; kc < 4; ++kc) {
                h8_t bf = hb[kc * 4 + quad];
                acc0 = __builtin_amdgcn_mfma_f32_16x16x32_f16(a[0][kc], bf, acc0, 0, 0, 0);
                acc1 = __builtin_amdgcn_mfma_f32_16x16x32_f16(a[1][kc], bf, acc1, 0, 0, 0);
                acc2 = __builtin_amdgcn_mfma_f32_16x16x32_f16(a[2][kc], bf, acc2, 0, 0, 0);
                acc3 = __builtin_amdgcn_mfma_f32_16x16x32_f16(a[3][kc], bf, acc3, 0, 0, 0);
            }

            // static-index select of own C row (rg = col&3) + xg add
            float v01, v23;
            v01 = sel1 ? acc0[1] : acc0[0];  v23 = sel1 ? acc0[3] : acc0[2];
            float pi = (sel2 ? v23 : v01) + xv0;
            v01 = sel1 ? acc1[1] : acc1[0];  v23 = sel1 ? acc1[3] : acc1[2];
            float pf = (sel2 ? v23 : v01) + xv1;
            v01 = sel1 ? acc2[1] : acc2[0];  v23 = sel1 ? acc2[3] : acc2[2];
            float pg = (sel2 ? v23 : v01) + xv2;
            v01 = sel1 ? acc3[1] : acc3[0];  v23 = sel1 ? acc3[3] : acc3[2];
            float po = (sel2 ? v23 : v01) + xv3;

            float ia = fsig(pi);
            float fa = fsig(pf);
            float ga = ftanh(pg);
            float oa = fsig(po);
            c = fa * c + ia * ga;             // redundant x4 across col groups
            float hv = oa * ftanh(c);
            hlast = hv;

            if (col < 4) {                    // unique writer per hid (col == rg)
                h_buf[(s + 1) & 1][hid] = __float2half(hv);
                *outp = hv;                   // store stays in flight
            }
            outp += BATCH * HID;
            bar();   // lgkmcnt-only: h visible, globals keep flowing
        }
    }

    if (col < 4) {
        out[SBH + (long)bidx * HID + hid]                     = hlast;  // h_T
        out[SBH + (long)BATCH * HID + (long)bidx * HID + hid] = c;      // c_T
    }
}

// ---------------------------------------------------------------------------
extern "C" void kernel_launch(void* const* d_in, const int* in_sizes, int n_in,
                              void* d_out, int out_size, void* d_ws, size_t ws_size,
                              hipStream_t stream) {
    const float* x  = (const float*)d_in[0];
    const float* V  = (const float*)d_in[1];
    const float* W  = (const float*)d_in[2];
    const float* b  = (const float*)d_in[3];
    const float* b2 = (const float*)d_in[4];
    float* out = (float*)d_out;
    __half* xg = (__half*)d_ws;   // 2048*128*512*2 = 268435456 B

    dim3 g1(G4 / 128, (S_LEN * BATCH) / 128);   // (4, 2048)
    xg_gemm<<<g1, dim3(256), 0, stream>>>(x, V, b, b2, xg);
    lstm_scan<<<dim3(BATCH), dim3(512), 0, stream>>>(xg, W, out);
}